// Round 5
// baseline (100.549 us; speedup 1.0000x reference)
//
#include <hip/hip_runtime.h>
#include <math.h>

// spikeLN: s = OATN-quantize(x); y = LayerNorm_D(s) * weight + bias
// x: [B*S, D] f32, D = 4096. weight/bias: [D] f32. out: [B*S, D] f32.

#define LN_D      4096
#define LN_BLOCK  512
// each thread: 2 x f32x4 = 8 elements; 512 threads * 8 = 4096 = D.
// w/b are PRELOADED before the reduction barrier so their L2-hit latency
// hides under quantize+reduce instead of sitting on the post-barrier
// critical path (compiler cannot hoist loads across __syncthreads).

// native clang vector (required by __builtin_nontemporal_*)
typedef float f32x4 __attribute__((ext_vector_type(4)));

// Saturation constants: vmax * (1 - 2^-16)
#define SAT10  ((float)(10.0  * (1.0 - 1.0/65536.0)))
#define SAT500 ((float)(500.0 * (1.0 - 1.0/65536.0)))

__device__ __forceinline__ float oatn_f32(float xf) {
    // clip to [-500, 500]
    float xc = fminf(fmaxf(xf, -500.0f), 500.0f);
    float a  = fabsf(xc);
    bool small = (a < 10.0f);
    // divide-free: floor(a/vmax*65536) == floor(a * (65536/vmax))
    float mul   = small ? (65536.0f / 10.0f) : (65536.0f / 500.0f);
    float scale = small ? (10.0f / 65536.0f) : (500.0f / 65536.0f);  // exact in f32
    float sat   = small ? SAT10 : SAT500;
    float q = floorf(a * mul) * scale;
    q = fminf(q, sat);
    return copysignf(q, xc);
}

__global__ __launch_bounds__(LN_BLOCK, 4)
void spikeln_kernel(const float* __restrict__ x,
                    const float* __restrict__ w,
                    const float* __restrict__ b,
                    float* __restrict__ out)
{
    const int row = blockIdx.x;
    const size_t base = (size_t)row * LN_D;
    const f32x4* __restrict__ x4 = reinterpret_cast<const f32x4*>(x + base);
    f32x4* __restrict__ y4       = reinterpret_cast<f32x4*>(out + base);
    const f32x4* __restrict__ w4 = reinterpret_cast<const f32x4*>(w);
    const f32x4* __restrict__ b4 = reinterpret_cast<const f32x4*>(b);

    const int tid  = threadIdx.x;
    const int lane = tid & 63;
    const int wid  = tid >> 6;   // 8 waves

    // Issue x loads first (oldest in vmcnt queue), then w/b (stay in flight
    // through quantize + reduce + barrier; they are L2-resident after the
    // first few blocks).
    f32x4 v0 = __builtin_nontemporal_load(&x4[tid]);
    f32x4 v1 = __builtin_nontemporal_load(&x4[tid + LN_BLOCK]);
    f32x4 wv0 = w4[tid];
    f32x4 wv1 = w4[tid + LN_BLOCK];
    f32x4 bv0 = b4[tid];
    f32x4 bv1 = b4[tid + LN_BLOCK];

    float s[8];
    float psum = 0.0f;
    float psq  = 0.0f;

    {
        float q0 = oatn_f32(v0.x), q1 = oatn_f32(v0.y);
        float q2 = oatn_f32(v0.z), q3 = oatn_f32(v0.w);
        s[0] = q0; s[1] = q1; s[2] = q2; s[3] = q3;
        psum += (q0 + q1) + (q2 + q3);
        psq = fmaf(q0, q0, psq); psq = fmaf(q1, q1, psq);
        psq = fmaf(q2, q2, psq); psq = fmaf(q3, q3, psq);
    }
    {
        float q0 = oatn_f32(v1.x), q1 = oatn_f32(v1.y);
        float q2 = oatn_f32(v1.z), q3 = oatn_f32(v1.w);
        s[4] = q0; s[5] = q1; s[6] = q2; s[7] = q3;
        psum += (q0 + q1) + (q2 + q3);
        psq = fmaf(q0, q0, psq); psq = fmaf(q1, q1, psq);
        psq = fmaf(q2, q2, psq); psq = fmaf(q3, q3, psq);
    }

    // Single reduction round: (sum, sumsq) together, one barrier.
    __shared__ float red[16];
    #pragma unroll
    for (int off = 32; off > 0; off >>= 1) {
        psum += __shfl_xor(psum, off);
        psq  += __shfl_xor(psq,  off);
    }
    if (lane == 0) { red[wid] = psum; red[8 + wid] = psq; }
    __syncthreads();

    float sum = 0.0f, sq = 0.0f;
    #pragma unroll
    for (int i = 0; i < 8; ++i) { sum += red[i]; sq += red[8 + i]; }
    const float mu  = sum * (1.0f / (float)LN_D);
    float var = sq * (1.0f / (float)LN_D) - mu * mu;
    var = fmaxf(var, 0.0f);
    const float rstd = 1.0f / sqrtf(var + 1e-5f);

    // Store phase: w/b already in registers — first store issues immediately.
    {
        f32x4 o;
        o.x = ((s[0] - mu) * rstd) * wv0.x + bv0.x;
        o.y = ((s[1] - mu) * rstd) * wv0.y + bv0.y;
        o.z = ((s[2] - mu) * rstd) * wv0.z + bv0.z;
        o.w = ((s[3] - mu) * rstd) * wv0.w + bv0.w;
        __builtin_nontemporal_store(o, &y4[tid]);
    }
    {
        f32x4 o;
        o.x = ((s[4] - mu) * rstd) * wv1.x + bv1.x;
        o.y = ((s[5] - mu) * rstd) * wv1.y + bv1.y;
        o.z = ((s[6] - mu) * rstd) * wv1.z + bv1.z;
        o.w = ((s[7] - mu) * rstd) * wv1.w + bv1.w;
        __builtin_nontemporal_store(o, &y4[tid + LN_BLOCK]);
    }
}

extern "C" void kernel_launch(void* const* d_in, const int* in_sizes, int n_in,
                              void* d_out, int out_size, void* d_ws, size_t ws_size,
                              hipStream_t stream) {
    const float* x = (const float*)d_in[0];
    const float* w = (const float*)d_in[1];
    const float* b = (const float*)d_in[2];
    float* out = (float*)d_out;

    const int nrows = in_sizes[0] / LN_D;  // B*S = 16384
    spikeln_kernel<<<nrows, LN_BLOCK, 0, stream>>>(x, w, b, out);
}

// Round 6
// 91.505 us; speedup vs baseline: 1.0988x; 1.0988x over previous
//
#include <hip/hip_runtime.h>
#include <math.h>

// spikeLN: s = OATN-quantize(x); y = LayerNorm_D(s) * weight + bias
// x: [B*S, D] f32, D = 4096. weight/bias: [D] f32. out: [B*S, D] f32.
//
// R4 configuration (best measured: 91.2 us = 93.6% of the 6.29 TB/s
// mixed-stream HBM ceiling). R5's w/b register-preload regressed -10%
// (occupancy halved + no latency worth hiding) — reverted.

#define LN_D      4096
#define LN_BLOCK  512
// each thread: 2 x f32x4 = 8 elements; 512 threads * 8 = 4096 = D
// launch_bounds(512,8): forces VGPR<=64 -> 32 waves/CU (4 blocks/CU).

// native clang vector (required by __builtin_nontemporal_*)
typedef float f32x4 __attribute__((ext_vector_type(4)));

// Saturation constants: vmax * (1 - 2^-16)
#define SAT10  ((float)(10.0  * (1.0 - 1.0/65536.0)))
#define SAT500 ((float)(500.0 * (1.0 - 1.0/65536.0)))

__device__ __forceinline__ float oatn_f32(float xf) {
    // clip to [-500, 500]
    float xc = fminf(fmaxf(xf, -500.0f), 500.0f);
    float a  = fabsf(xc);
    bool small = (a < 10.0f);
    // divide-free: floor(a/vmax*65536) == floor(a * (65536/vmax))
    float mul   = small ? (65536.0f / 10.0f) : (65536.0f / 500.0f);
    float scale = small ? (10.0f / 65536.0f) : (500.0f / 65536.0f);  // exact in f32
    float sat   = small ? SAT10 : SAT500;
    float q = floorf(a * mul) * scale;
    q = fminf(q, sat);
    return copysignf(q, xc);
}

__global__ __launch_bounds__(LN_BLOCK, 8)
void spikeln_kernel(const float* __restrict__ x,
                    const float* __restrict__ w,
                    const float* __restrict__ b,
                    float* __restrict__ out)
{
    const int row = blockIdx.x;
    const size_t base = (size_t)row * LN_D;
    const f32x4* __restrict__ x4 = reinterpret_cast<const f32x4*>(x + base);
    f32x4* __restrict__ y4       = reinterpret_cast<f32x4*>(out + base);
    const f32x4* __restrict__ w4 = reinterpret_cast<const f32x4*>(w);
    const f32x4* __restrict__ b4 = reinterpret_cast<const f32x4*>(b);

    const int tid  = threadIdx.x;
    const int lane = tid & 63;
    const int wid  = tid >> 6;   // 8 waves

    float s[8];
    float psum = 0.0f;
    float psq  = 0.0f;

    // Pass 1: streaming load + quantize into registers, partial (sum, sumsq)
    #pragma unroll
    for (int c = 0; c < 2; ++c) {
        f32x4 v = __builtin_nontemporal_load(&x4[tid + c * LN_BLOCK]);
        float q0 = oatn_f32(v.x);
        float q1 = oatn_f32(v.y);
        float q2 = oatn_f32(v.z);
        float q3 = oatn_f32(v.w);
        s[c * 4 + 0] = q0;
        s[c * 4 + 1] = q1;
        s[c * 4 + 2] = q2;
        s[c * 4 + 3] = q3;
        psum += (q0 + q1) + (q2 + q3);
        psq = fmaf(q0, q0, psq);
        psq = fmaf(q1, q1, psq);
        psq = fmaf(q2, q2, psq);
        psq = fmaf(q3, q3, psq);
    }

    // Single reduction round: (sum, sumsq) together, one barrier.
    __shared__ float red[16];
    #pragma unroll
    for (int off = 32; off > 0; off >>= 1) {
        psum += __shfl_xor(psum, off);
        psq  += __shfl_xor(psq,  off);
    }
    if (lane == 0) { red[wid] = psum; red[8 + wid] = psq; }
    __syncthreads();

    float sum = 0.0f, sq = 0.0f;
    #pragma unroll
    for (int i = 0; i < 8; ++i) { sum += red[i]; sq += red[8 + i]; }
    const float mu  = sum * (1.0f / (float)LN_D);
    float var = sq * (1.0f / (float)LN_D) - mu * mu;
    var = fmaxf(var, 0.0f);
    const float rstd = 1.0f / sqrtf(var + 1e-5f);

    // Pass 2: normalize, affine, streaming store (w/b are L1-resident)
    #pragma unroll
    for (int c = 0; c < 2; ++c) {
        const int idx = tid + c * LN_BLOCK;
        f32x4 wv = w4[idx];
        f32x4 bv = b4[idx];
        f32x4 o;
        o.x = ((s[c * 4 + 0] - mu) * rstd) * wv.x + bv.x;
        o.y = ((s[c * 4 + 1] - mu) * rstd) * wv.y + bv.y;
        o.z = ((s[c * 4 + 2] - mu) * rstd) * wv.z + bv.z;
        o.w = ((s[c * 4 + 3] - mu) * rstd) * wv.w + bv.w;
        __builtin_nontemporal_store(o, &y4[idx]);
    }
}

extern "C" void kernel_launch(void* const* d_in, const int* in_sizes, int n_in,
                              void* d_out, int out_size, void* d_ws, size_t ws_size,
                              hipStream_t stream) {
    const float* x = (const float*)d_in[0];
    const float* w = (const float*)d_in[1];
    const float* b = (const float*)d_in[2];
    float* out = (float*)d_out;

    const int nrows = in_sizes[0] / LN_D;  // B*S = 16384
    spikeln_kernel<<<nrows, LN_BLOCK, 0, stream>>>(x, w, b, out);
}